// Round 6
// baseline (130.880 us; speedup 1.0000x reference)
//
#include <hip/hip_runtime.h>
#include <math.h>

#define NB 32
#define CC 64
#define LL 1024
#define EPS 1e-6f
#define SCALE 14.42695040888963f   // 10*log2(e): exp(10*s) == exp2(SCALE*s)

typedef __attribute__((ext_vector_type(8))) __bf16 bf16x8;
typedef __attribute__((ext_vector_type(4))) float f32x4;

#define GLB(p) ((__attribute__((address_space(1))) void*)(p))
#define LDS(p) ((__attribute__((address_space(3))) void*)(p))

// DPP helpers: 16-lane butterfly on the VALU pipe (NOT ds_bpermute).
// 0xB1=quad_perm(1,0,3,2) [xor1], 0x4E=quad_perm(2,3,0,1) [xor2],
// 0x141=row_half_mirror [pairs across 4-groups], 0x140=row_mirror [across 8].
template <int CTRL>
__device__ __forceinline__ float dppf(float x) {
    return __int_as_float(__builtin_amdgcn_update_dpp(
            0, __float_as_int(x), CTRL, 0xF, 0xF, true));
}
template <int CTRL>
__device__ __forceinline__ unsigned dppu(unsigned x) {
    return (unsigned)__builtin_amdgcn_update_dpp(
            0, (int)x, CTRL, 0xF, 0xF, true);
}

// ws byte layout:
//   At      @ 0         (4 MB)   bf16 [32][1024][64]  rgb, normalized*SCALE, [l][c]
//   Bt      @ 4194304   (4 MB)   bf16 [32][1024][64]  ir, normalized, [l][c]
//   row_sum @ 8388608   (128 KB) f32[32768]   (final, written by merge)
//   col_sum @ 8519680   (128 KB) f32[32768]
//   row_pk  @ 8650752   (128 KB) u32[32768]  (expbits&~1023)|(1023-j)
//   col_pk  @ 8781824   (128 KB) u32[32768]  (expbits&~1023)|(1023-i)
//   partial @ 8912896   (256 B)  f32[64] loss partials
//   rps     @ 9437184   (256 KB) f32[2][32768]      row-sum partials per j-half
//   rpp     @ 9699328   (256 KB) u32[2][32768]      row-pk  partials per j-half
//   cps     @ 9961472   (2 MB)   f32[32][16][1024]  col-sum partials per i-tile
//   cpp     @ 12058624  (2 MB)   u32[32][16][1024]  col-pk  partials per i-tile
// No zero-init needed: every scratch word is direct-stored exactly once.

__global__ __launch_bounds__(256) void transpose_norm_kernel(
        const float* __restrict__ rgb, const float* __restrict__ ir,
        __bf16* __restrict__ At, __bf16* __restrict__ Bt) {
    __shared__ float tile[64][65];
    __shared__ float red[4][64];
    __shared__ float rn[64];

    const int t   = threadIdx.x;
    const int blk = blockIdx.x;
    const int in  = blk >> 9;
    const int b   = (blk >> 4) & 31;
    const int l0  = (blk & 15) << 6;
    const float* src = in ? ir : rgb;
    __bf16*      dst = in ? Bt : At;
    const float  sc  = in ? 1.0f : SCALE;   // fold exp2 prescale into rgb side

    const int lv = (t & 15) << 2;   // l within tile, step 4
    const int cv = t >> 4;          // c base lane, 0..15
    const float* sp = src + ((size_t)b << 16) + l0 + lv;
#pragma unroll
    for (int u = 0; u < 4; ++u) {
        int c = cv + (u << 4);
        float4 v = *(const float4*)(sp + ((size_t)c << 10));
        tile[c][lv + 0] = v.x;
        tile[c][lv + 1] = v.y;
        tile[c][lv + 2] = v.z;
        tile[c][lv + 3] = v.w;
    }
    __syncthreads();

    const int ll = t & 63, cg = t >> 6;
    float ssq = 0.f;
#pragma unroll
    for (int u = 0; u < 16; ++u) {
        float v = tile[cg * 16 + u][ll];
        ssq = fmaf(v, v, ssq);
    }
    red[cg][ll] = ssq;
    __syncthreads();
    if (t < 64) {
        float s = red[0][t] + red[1][t] + red[2][t] + red[3][t];
        rn[t] = sc / fmaxf(sqrtf(s), 1e-12f);
    }
    __syncthreads();

    const int lw  = t >> 2;
    const int cg2 = t & 3;
    const float r = rn[lw];
    bf16x8 v0, v1;
#pragma unroll
    for (int u = 0; u < 8; ++u)
        v0[u] = (__bf16)(tile[cg2 * 16 + u][lw] * r);
#pragma unroll
    for (int u = 0; u < 8; ++u)
        v1[u] = (__bf16)(tile[cg2 * 16 + 8 + u][lw] * r);
    size_t base = ((((size_t)b << 10) + l0 + lw) << 6) + cg2 * 16;
    *(bf16x8*)(dst + base)     = v0;
    *(bf16x8*)(dst + base + 8) = v1;
}

// Single-pass GEMM: S computed ONCE. Grid 1024 = batch(32) x itile(16) x
// jhalf(2): block owns rows [i0,+64) x cols [jh*512,+512).
//
// r5-r11 lesson (pipe accounting): all prior variants were DS-PIPE-bound:
// ds_read_b128 16/wave/chunk (4 waves redundantly reading the SAME B rows,
// ~5.1 us device-wide) + 144-160 shfl/wave (ds_bpermute, ~6.4 us) with a
// ~3x stall multiplier on serial shfl chains -> gemm pinned at 30-37 us
// in every structure. r12 attacks the DS pipe itself:
//   1. Wave owns 64i x 32j (not 16i x 128j): B-frags wave-exclusive ->
//      ds_read_b128 4/wave/chunk (4x cut). A-frags (8 bf16x8, 32 VGPR)
//      loaded once from global.
//   2. Row stats stay in REGISTERS (rsum/rpk[4][4], static indices) all
//      kernel; the m-fold (xor 1,2,4,8 within 16 lanes) runs on the VALU
//      pipe via DPP (quad_perm/mirrors) -- zero DS ops.
//   3. Col stats: in-register fold over the 4 row-groups, then only
//      xor16+xor32 shfl (8/wave/chunk) + masked write to a wave-exclusive
//      4 KB LDS tail (no cross-wave col fold in this layout).
// DS ops per wave-chunk: 56 -> ~14. LDS 38 KB; launch_bounds(256,3)
// (VGPR est ~115, cap 168 -- spill-safe per r9 lesson).
__global__ __launch_bounds__(256, 3) void gemm_stats_kernel(
        const __bf16* __restrict__ At, const __bf16* __restrict__ Bt,
        float* __restrict__ rps, unsigned* __restrict__ rpp,
        float* __restrict__ cps, unsigned* __restrict__ cpp) {
    __shared__ __bf16 bs[2][8192];       // 32 KB: dbuf x (128 rows x 64 bf16)
    __shared__ float2 coltail[512];      // 4 KB: per-col (sum, pk) -- wave-exclusive
    __shared__ float2 rowtail[4][64];    // 2 KB: per-wave row partials

    const int t   = threadIdx.x;
    const int blk = blockIdx.x;
    const int jh  = blk & 1;
    const int it  = (blk >> 1) & 15;
    const int bb  = blk >> 5;
    const int i0  = it << 6;
    const int w = t >> 6, lane = t & 63;
    const int m = lane & 15, q = lane >> 4;

    const size_t bbase = (size_t)bb << 16;
    const __bf16* Bg = Bt + bbase + ((size_t)jh << 15);   // + jh*512 rows*64

    // A fragments for ALL 4 row-groups: row = i0+16g+m, k-halves q*8 (+32).
    bf16x8 a[4][2];
#pragma unroll
    for (int g = 0; g < 4; ++g) {
        const __bf16* Ap = At + bbase + ((size_t)(i0 + 16 * g + m) << 6) + q * 8;
        a[g][0] = *(const bf16x8*)(Ap);
        a[g][1] = *(const bf16x8*)(Ap + 32);
    }

    // Swizzled fragment read offsets; global-side swizzle put segment s of
    // row r at slot s^(r&7). s0 -> k 0..31 (seg q), s1 -> k 32..63 (seg q^4).
    const int mbase = m * 64;
    const int s0 = (q ^ (m & 7)) << 3;
    const int s1 = ((q ^ 4) ^ (m & 7)) << 3;

    float    rsum[4][4];
    unsigned rpk[4][4];
#pragma unroll
    for (int g = 0; g < 4; ++g)
#pragma unroll
        for (int r = 0; r < 4; ++r) { rsum[g][r] = 0.f; rpk[g][r] = 0u; }

    // col-pack base: iinv = 1023 - (i0+16g+4q+r) = (Kb - 16g) - r.
    const unsigned Kb = 1023u - (unsigned)(i0 + 4 * q);

    // Staging geometry (per 128-row chunk): row r = rho*32 + (t>>3), seg
    // slot t&7, global seg = slot ^ (r&7).
    const int sr  = t >> 3;
    const int ssl = t & 7;

    // stage chunk 0 -> bs[0]
#pragma unroll
    for (int rho = 0; rho < 4; ++rho) {
        int r  = rho * 32 + sr;
        int sg = ssl ^ (r & 7);
        const __bf16* gp = Bg + ((size_t)r << 6) + sg * 8;
        __builtin_amdgcn_global_load_lds(GLB(gp),
                LDS(&bs[0][(rho << 11) + (w << 9)]), 16, 0, 0);
    }
    __syncthreads();   // chunk 0 ready

    for (int c = 0; c < 4; ++c) {
        const int cur = c & 1;
        if (c < 3) {   // issue async loads for chunk c+1 into the other buffer
#pragma unroll
            for (int rho = 0; rho < 4; ++rho) {
                int r  = rho * 32 + sr;
                int sg = ssl ^ (r & 7);
                const __bf16* gp = Bg + ((size_t)((c + 1) * 128 + r) << 6) + sg * 8;
                __builtin_amdgcn_global_load_lds(GLB(gp),
                        LDS(&bs[cur ^ 1][(rho << 11) + (w << 9)]), 16, 0, 0);
            }
        }
        // Wave w computes col-tiles {2w, 2w+1} of this chunk x all 64 rows.
#pragma unroll
        for (int u = 0; u < 2; ++u) {
            const int G = 2 * w + u;            // row-group of B within chunk
            const __bf16* pb = &bs[cur][(G << 10) + mbase];
            bf16x8 b0 = *(const bf16x8*)(pb + s0);
            bf16x8 b1 = *(const bf16x8*)(pb + s1);
            const int ctg = (jh << 5) + (c << 3) + G;
            const unsigned jinv = 1023u - (unsigned)((ctg << 4) + m);
            float csv = 0.f;
            unsigned pcv = 0u;
#pragma unroll
            for (int g = 0; g < 4; ++g) {
                f32x4 acc = (f32x4){0.f, 0.f, 0.f, 0.f};
                acc = __builtin_amdgcn_mfma_f32_16x16x32_bf16(a[g][0], b0, acc, 0, 0, 0);
                acc = __builtin_amdgcn_mfma_f32_16x16x32_bf16(a[g][1], b1, acc, 0, 0, 0);
                // C/D layout (verified r2-r6): row = i0+16g+4q+r, col = 16ctg+m.
                const unsigned Kg = Kb - 16u * (unsigned)g;
#pragma unroll
                for (int r = 0; r < 4; ++r) {
                    float e = __builtin_amdgcn_exp2f(acc[r]);   // SCALE in At
                    unsigned eb = __float_as_uint(e) & 0xFFFFFC00u;
                    rsum[g][r] += e;
                    unsigned pr = eb | jinv;
                    if (pr > rpk[g][r]) rpk[g][r] = pr;         // v_max_u32
                    unsigned pc = eb + (Kg - (unsigned)r);      // == eb | iinv
                    if (g == 0 && r == 0) { csv = e; pcv = pc; }
                    else { csv += e; if (pc > pcv) pcv = pc; }
                }
            }
            // Col fold: only q (xor16 + xor32) -- rows 16g+4q+r complete
            // in-register above. 4 shfl per u; masked single LDS write.
            csv += __shfl_xor(csv, 16, 64);
            csv += __shfl_xor(csv, 32, 64);
            unsigned o = (unsigned)__shfl_xor((int)pcv, 16, 64);
            if (o > pcv) pcv = o;
            o = (unsigned)__shfl_xor((int)pcv, 32, 64);
            if (o > pcv) pcv = o;
            if (q == 0) {
                float2 v; v.x = csv; v.y = __uint_as_float(pcv);
                coltail[(((c << 3) + G) << 4) + m] = v;   // wave-exclusive col
            }
        }
        // One barrier per chunk: (a) chunk c+1's staged loads complete,
        // (b) all waves done reading buf cur before c+2 re-stages it,
        // (c) coltail ds_writes drained (lgkmcnt).
        __syncthreads();
    }

    // Row fold: m-butterfly entirely on the VALU pipe via DPP. After the 4
    // steps every lane in each 16-lane row holds the fold; lanes m==0 write
    // per-wave partials (rows 16g+4q+r, this wave's 128-j quarter-set).
#pragma unroll
    for (int g = 0; g < 4; ++g)
#pragma unroll
        for (int r = 0; r < 4; ++r) {
            float s = rsum[g][r];
            s += dppf<0xB1>(s);
            s += dppf<0x4E>(s);
            s += dppf<0x141>(s);
            s += dppf<0x140>(s);
            unsigned p = rpk[g][r];
            unsigned o;
            o = dppu<0xB1>(p);  if (o > p) p = o;
            o = dppu<0x4E>(p);  if (o > p) p = o;
            o = dppu<0x141>(p); if (o > p) p = o;
            o = dppu<0x140>(p); if (o > p) p = o;
            if (m == 0) {
                float2 v; v.x = s; v.y = __uint_as_float(p);
                rowtail[w][g * 16 + q * 4 + r] = v;
            }
        }
    __syncthreads();   // tails visible

    // Row epilogue: fold the 4 waves' j-quarter partials, store this
    // j-half's partials (merge folds the 2 halves).
    if (t < 64) {
        float2 v0 = rowtail[0][t], v1 = rowtail[1][t];
        float2 v2 = rowtail[2][t], v3 = rowtail[3][t];
        float s = v0.x + v1.x + v2.x + v3.x;
        unsigned p = __float_as_uint(v0.y);
        unsigned o;
        o = __float_as_uint(v1.y); if (o > p) p = o;
        o = __float_as_uint(v2.y); if (o > p) p = o;
        o = __float_as_uint(v3.y); if (o > p) p = o;
        int idx = (bb << 10) + i0 + t;
        rps[(jh << 15) + idx] = s;
        rpp[(jh << 15) + idx] = p;
    }

    // Col epilogue: coltail is already complete over the block's 64 rows;
    // coalesced store of ONE partial per (block, col).
#pragma unroll
    for (int v = 0; v < 2; ++v) {
        int cj = (v << 8) + t;              // 0..511 within the j-half
        float2 pr = coltail[cj];
        int gidx = (((bb << 4) + it) << 10) + (jh << 9) + cj;
        cps[gidx] = pr.x;
        cpp[gidx] = __float_as_uint(pr.y);
    }
}

// Fold row partials (2 j-halves) and col partials (16 i-tiles) into the
// final stats arrays. Tie-break: umax on packed (bits|inv_index) keeps the
// smaller index on equal truncated value = first-occurrence, matching ref.
__global__ __launch_bounds__(256) void merge_kernel(
        const float* __restrict__ rps, const unsigned* __restrict__ rpp,
        const float* __restrict__ cps, const unsigned* __restrict__ cpp,
        float* __restrict__ row_sum, unsigned* __restrict__ row_pk,
        float* __restrict__ col_sum, unsigned* __restrict__ col_pk) {
    int p = blockIdx.x * 256 + threadIdx.x;   // 32768
    // rows: 2 partials
    float rs = rps[p] + rps[32768 + p];
    unsigned ra = rpp[p], rb = rpp[32768 + p];
    row_sum[p] = rs;
    row_pk[p]  = ra > rb ? ra : rb;
    // cols: 16 partials, stride 1024 dwords (j contiguous -> coalesced)
    int bb = p >> 10, j = p & 1023;
    const float*    cq = cps + (((size_t)bb << 14) + j);
    const unsigned* cr = cpp + (((size_t)bb << 14) + j);
    float s = 0.f;
    unsigned pk = 0u;
#pragma unroll
    for (int k = 0; k < 16; ++k) {
        s += cq[(size_t)k << 10];
        unsigned o = cr[(size_t)k << 10];
        pk = pk > o ? pk : o;
    }
    col_sum[p] = s;
    col_pk[p]  = pk;
}

// Reference broadcasting: trailing /(sum+EPS) factors are indexed by ELEMENT
// position, not by argmax. Writes per-block partials (no atomics, no init).
__global__ __launch_bounds__(256) void loss_kernel2(
        const float* __restrict__ row_sum, const unsigned* __restrict__ row_pk,
        const float* __restrict__ col_sum, const unsigned* __restrict__ col_pk,
        float* __restrict__ partial) {
    int t = blockIdx.x * 256 + threadIdx.x;
    float acc = 0.f;
#pragma unroll
    for (int it = 0; it < 4; ++it) {
        int p = t + it * 16384;
        if (p < NB * LL) {
            unsigned pk2 = row_pk[p];
            float m2 = __uint_as_float(pk2 & 0xFFFFFC00u);
            int j = 1023 - (int)(pk2 & 1023u);
            float s2 = row_sum[p];
            float s1 = col_sum[p];
            unsigned pk1 = col_pk[(p & ~1023) + j];
            float m1 = __uint_as_float(pk1 & 0xFFFFFC00u);
            acc += logf((m2 / (s2 + EPS)) * (m1 / (s1 + EPS)));
        } else {
            int p2 = p - NB * LL;
            unsigned pk1 = col_pk[p2];
            float m1 = __uint_as_float(pk1 & 0xFFFFFC00u);
            int i = 1023 - (int)(pk1 & 1023u);
            float s1 = col_sum[p2];
            float s2 = row_sum[p2];
            unsigned pk2 = row_pk[(p2 & ~1023) + i];
            float m2 = __uint_as_float(pk2 & 0xFFFFFC00u);
            acc += logf((m1 / (s1 + EPS)) * (m2 / (s2 + EPS)));
        }
    }
#pragma unroll
    for (int off = 32; off > 0; off >>= 1) acc += __shfl_down(acc, off, 64);
    __shared__ float wsum[4];
    int lane = threadIdx.x & 63, w = threadIdx.x >> 6;
    if (lane == 0) wsum[w] = acc;
    __syncthreads();
    if (threadIdx.x == 0)
        partial[blockIdx.x] = wsum[0] + wsum[1] + wsum[2] + wsum[3];
}

__global__ void finalize_kernel(const float* __restrict__ partial,
                                float* __restrict__ out) {
    float v = partial[threadIdx.x];
#pragma unroll
    for (int off = 32; off > 0; off >>= 1) v += __shfl_down(v, off, 64);
    if (threadIdx.x == 0) out[0] = -v / (float)(2 * NB * LL);
}

extern "C" void kernel_launch(void* const* d_in, const int* in_sizes, int n_in,
                              void* d_out, int out_size, void* d_ws, size_t ws_size,
                              hipStream_t stream) {
    const float* rgb = (const float*)d_in[0];
    const float* ir  = (const float*)d_in[1];
    char* wsb = (char*)d_ws;

    __bf16*   At      = (__bf16*)(wsb);
    __bf16*   Bt      = (__bf16*)(wsb + 4194304);
    float*    row_sum = (float*)(wsb + 8388608);
    float*    col_sum = (float*)(wsb + 8519680);
    unsigned* row_pk  = (unsigned*)(wsb + 8650752);
    unsigned* col_pk  = (unsigned*)(wsb + 8781824);
    float*    partial = (float*)(wsb + 8912896);
    float*    rps     = (float*)(wsb + 9437184);
    unsigned* rpp     = (unsigned*)(wsb + 9699328);
    float*    cps     = (float*)(wsb + 9961472);
    unsigned* cpp     = (unsigned*)(wsb + 12058624);

    transpose_norm_kernel<<<1024, 256, 0, stream>>>(rgb, ir, At, Bt);
    gemm_stats_kernel<<<1024, 256, 0, stream>>>(At, Bt, rps, rpp, cps, cpp);
    merge_kernel<<<128, 256, 0, stream>>>(rps, rpp, cps, cpp,
                                          row_sum, row_pk, col_sum, col_pk);
    loss_kernel2<<<64, 256, 0, stream>>>(row_sum, row_pk, col_sum, col_pk, partial);
    finalize_kernel<<<1, 64, 0, stream>>>(partial, (float*)d_out);
}

// Round 7
// 101.946 us; speedup vs baseline: 1.2838x; 1.2838x over previous
//
#include <hip/hip_runtime.h>
#include <math.h>

#define NB 32
#define CC 64
#define LL 1024
#define EPS 1e-6f
#define SCALE 14.42695040888963f   // 10*log2(e): exp(10*s) == exp2(SCALE*s)

typedef __attribute__((ext_vector_type(8))) __bf16 bf16x8;
typedef __attribute__((ext_vector_type(4))) float f32x4;

#define GLB(p) ((__attribute__((address_space(1))) void*)(p))
#define LDS(p) ((__attribute__((address_space(3))) void*)(p))

// DPP helpers: 16-lane butterfly on the VALU pipe (NOT ds_bpermute).
// 0xB1=quad_perm(1,0,3,2) [xor1], 0x4E=quad_perm(2,3,0,1) [xor2],
// 0x141=row_half_mirror [xor4 within 8], 0x140=row_mirror [xor8 within 16].
template <int CTRL>
__device__ __forceinline__ float dppf(float x) {
    return __int_as_float(__builtin_amdgcn_update_dpp(
            0, __float_as_int(x), CTRL, 0xF, 0xF, true));
}
template <int CTRL>
__device__ __forceinline__ unsigned dppu(unsigned x) {
    return (unsigned)__builtin_amdgcn_update_dpp(
            0, (int)x, CTRL, 0xF, 0xF, true);
}

// ws byte layout:
//   At      @ 0         (4 MB)   bf16 [32][1024][64]  rgb, normalized*SCALE, [l][c]
//   Bt      @ 4194304   (4 MB)   bf16 [32][1024][64]  ir, normalized, [l][c]
//   row_sum @ 8388608   (128 KB) f32[32768]   (final, written by merge)
//   col_sum @ 8519680   (128 KB) f32[32768]
//   row_pk  @ 8650752   (128 KB) u32[32768]  (expbits&~1023)|(1023-j)
//   col_pk  @ 8781824   (128 KB) u32[32768]  (expbits&~1023)|(1023-i)
//   partial @ 8912896   (256 B)  f32[64] loss partials
//   rps     @ 9437184   (256 KB) f32[2][32768]      row-sum partials per j-half
//   rpp     @ 9699328   (256 KB) u32[2][32768]      row-pk  partials per j-half
//   cps     @ 9961472   (2 MB)   f32[32][16][1024]  col-sum partials per i-tile
//   cpp     @ 12058624  (2 MB)   u32[32][16][1024]  col-pk  partials per i-tile
// No zero-init needed: every scratch word is direct-stored exactly once.

__global__ __launch_bounds__(256) void transpose_norm_kernel(
        const float* __restrict__ rgb, const float* __restrict__ ir,
        __bf16* __restrict__ At, __bf16* __restrict__ Bt) {
    __shared__ float tile[64][65];
    __shared__ float red[4][64];
    __shared__ float rn[64];

    const int t   = threadIdx.x;
    const int blk = blockIdx.x;
    const int in  = blk >> 9;
    const int b   = (blk >> 4) & 31;
    const int l0  = (blk & 15) << 6;
    const float* src = in ? ir : rgb;
    __bf16*      dst = in ? Bt : At;
    const float  sc  = in ? 1.0f : SCALE;   // fold exp2 prescale into rgb side

    const int lv = (t & 15) << 2;   // l within tile, step 4
    const int cv = t >> 4;          // c base lane, 0..15
    const float* sp = src + ((size_t)b << 16) + l0 + lv;
#pragma unroll
    for (int u = 0; u < 4; ++u) {
        int c = cv + (u << 4);
        float4 v = *(const float4*)(sp + ((size_t)c << 10));
        tile[c][lv + 0] = v.x;
        tile[c][lv + 1] = v.y;
        tile[c][lv + 2] = v.z;
        tile[c][lv + 3] = v.w;
    }
    __syncthreads();

    const int ll = t & 63, cg = t >> 6;
    float ssq = 0.f;
#pragma unroll
    for (int u = 0; u < 16; ++u) {
        float v = tile[cg * 16 + u][ll];
        ssq = fmaf(v, v, ssq);
    }
    red[cg][ll] = ssq;
    __syncthreads();
    if (t < 64) {
        float s = red[0][t] + red[1][t] + red[2][t] + red[3][t];
        rn[t] = sc / fmaxf(sqrtf(s), 1e-12f);
    }
    __syncthreads();

    const int lw  = t >> 2;
    const int cg2 = t & 3;
    const float r = rn[lw];
    bf16x8 v0, v1;
#pragma unroll
    for (int u = 0; u < 8; ++u)
        v0[u] = (__bf16)(tile[cg2 * 16 + u][lw] * r);
#pragma unroll
    for (int u = 0; u < 8; ++u)
        v1[u] = (__bf16)(tile[cg2 * 16 + 8 + u][lw] * r);
    size_t base = ((((size_t)b << 10) + l0 + lw) << 6) + cg2 * 16;
    *(bf16x8*)(dst + base)     = v0;
    *(bf16x8*)(dst + base + 8) = v1;
}

// Single-pass GEMM: S computed ONCE. Grid 1024 = batch(32) x itile(16) x
// jhalf(2): block owns rows [i0,+64) x cols [jh*512,+512).
//
// r12 (round 6) verified this dataflow end-to-end (passed, absmax 0.0) and
// cut DS ops per wave-chunk 56 -> 14 (wave-exclusive B-frags, DPP row fold,
// q-only col fold). Its one flaw: __launch_bounds__(256,3) imposed a VGPR
// cap at the 128 HW step while live state needs ~115-130 -> the allocator
// demoted a[4][2] + rsum/rpk[4][4] to SCRATCH (~330 B/thread: FETCH 51 MB,
// WRITE 86 MB, VGPR_Count 84, gemm 64 us). Same failure mode as r9.
//
// r13 = r12 with the budget freed: plain __launch_bounds__(256) (cap 256).
// Expected VGPR ~115-140, localMem 0; occupancy 2-4 blocks/CU (LDS 38 KB
// allows 4). Everything else byte-identical to the verified round-6 kernel.
__global__ __launch_bounds__(256) void gemm_stats_kernel(
        const __bf16* __restrict__ At, const __bf16* __restrict__ Bt,
        float* __restrict__ rps, unsigned* __restrict__ rpp,
        float* __restrict__ cps, unsigned* __restrict__ cpp) {
    __shared__ __bf16 bs[2][8192];       // 32 KB: dbuf x (128 rows x 64 bf16)
    __shared__ float2 coltail[512];      // 4 KB: per-col (sum, pk) -- wave-exclusive
    __shared__ float2 rowtail[4][64];    // 2 KB: per-wave row partials

    const int t   = threadIdx.x;
    const int blk = blockIdx.x;
    const int jh  = blk & 1;
    const int it  = (blk >> 1) & 15;
    const int bb  = blk >> 5;
    const int i0  = it << 6;
    const int w = t >> 6, lane = t & 63;
    const int m = lane & 15, q = lane >> 4;

    const size_t bbase = (size_t)bb << 16;
    const __bf16* Bg = Bt + bbase + ((size_t)jh << 15);   // + jh*512 rows*64

    // A fragments for ALL 4 row-groups: row = i0+16g+m, k-halves q*8 (+32).
    bf16x8 a[4][2];
#pragma unroll
    for (int g = 0; g < 4; ++g) {
        const __bf16* Ap = At + bbase + ((size_t)(i0 + 16 * g + m) << 6) + q * 8;
        a[g][0] = *(const bf16x8*)(Ap);
        a[g][1] = *(const bf16x8*)(Ap + 32);
    }

    // Swizzled fragment read offsets; global-side swizzle put segment s of
    // row r at slot s^(r&7). s0 -> k 0..31 (seg q), s1 -> k 32..63 (seg q^4).
    const int mbase = m * 64;
    const int s0 = (q ^ (m & 7)) << 3;
    const int s1 = ((q ^ 4) ^ (m & 7)) << 3;

    float    rsum[4][4];
    unsigned rpk[4][4];
#pragma unroll
    for (int g = 0; g < 4; ++g)
#pragma unroll
        for (int r = 0; r < 4; ++r) { rsum[g][r] = 0.f; rpk[g][r] = 0u; }

    // col-pack base: iinv = 1023 - (i0+16g+4q+r) = (Kb - 16g) - r.
    const unsigned Kb = 1023u - (unsigned)(i0 + 4 * q);

    // Staging geometry (per 128-row chunk): row r = rho*32 + (t>>3), seg
    // slot t&7, global seg = slot ^ (r&7).
    const int sr  = t >> 3;
    const int ssl = t & 7;

    // stage chunk 0 -> bs[0]
#pragma unroll
    for (int rho = 0; rho < 4; ++rho) {
        int r  = rho * 32 + sr;
        int sg = ssl ^ (r & 7);
        const __bf16* gp = Bg + ((size_t)r << 6) + sg * 8;
        __builtin_amdgcn_global_load_lds(GLB(gp),
                LDS(&bs[0][(rho << 11) + (w << 9)]), 16, 0, 0);
    }
    __syncthreads();   // chunk 0 ready

    for (int c = 0; c < 4; ++c) {
        const int cur = c & 1;
        if (c < 3) {   // issue async loads for chunk c+1 into the other buffer
#pragma unroll
            for (int rho = 0; rho < 4; ++rho) {
                int r  = rho * 32 + sr;
                int sg = ssl ^ (r & 7);
                const __bf16* gp = Bg + ((size_t)((c + 1) * 128 + r) << 6) + sg * 8;
                __builtin_amdgcn_global_load_lds(GLB(gp),
                        LDS(&bs[cur ^ 1][(rho << 11) + (w << 9)]), 16, 0, 0);
            }
        }
        // Wave w computes col-tiles {2w, 2w+1} of this chunk x all 64 rows.
#pragma unroll
        for (int u = 0; u < 2; ++u) {
            const int G = 2 * w + u;            // row-group of B within chunk
            const __bf16* pb = &bs[cur][(G << 10) + mbase];
            bf16x8 b0 = *(const bf16x8*)(pb + s0);
            bf16x8 b1 = *(const bf16x8*)(pb + s1);
            const int ctg = (jh << 5) + (c << 3) + G;
            const unsigned jinv = 1023u - (unsigned)((ctg << 4) + m);
            float csv = 0.f;
            unsigned pcv = 0u;
#pragma unroll
            for (int g = 0; g < 4; ++g) {
                f32x4 acc = (f32x4){0.f, 0.f, 0.f, 0.f};
                acc = __builtin_amdgcn_mfma_f32_16x16x32_bf16(a[g][0], b0, acc, 0, 0, 0);
                acc = __builtin_amdgcn_mfma_f32_16x16x32_bf16(a[g][1], b1, acc, 0, 0, 0);
                // C/D layout (verified r2-r6): row = i0+16g+4q+r, col = 16ctg+m.
                const unsigned Kg = Kb - 16u * (unsigned)g;
#pragma unroll
                for (int r = 0; r < 4; ++r) {
                    float e = __builtin_amdgcn_exp2f(acc[r]);   // SCALE in At
                    unsigned eb = __float_as_uint(e) & 0xFFFFFC00u;
                    rsum[g][r] += e;
                    unsigned pr = eb | jinv;
                    if (pr > rpk[g][r]) rpk[g][r] = pr;         // v_max_u32
                    unsigned pc = eb + (Kg - (unsigned)r);      // == eb | iinv
                    if (g == 0 && r == 0) { csv = e; pcv = pc; }
                    else { csv += e; if (pc > pcv) pcv = pc; }
                }
            }
            // Col fold: only q (xor16 + xor32) -- rows 16g+4q+r complete
            // in-register above. 4 shfl per u; masked single LDS write.
            csv += __shfl_xor(csv, 16, 64);
            csv += __shfl_xor(csv, 32, 64);
            unsigned o = (unsigned)__shfl_xor((int)pcv, 16, 64);
            if (o > pcv) pcv = o;
            o = (unsigned)__shfl_xor((int)pcv, 32, 64);
            if (o > pcv) pcv = o;
            if (q == 0) {
                float2 v; v.x = csv; v.y = __uint_as_float(pcv);
                coltail[(((c << 3) + G) << 4) + m] = v;   // wave-exclusive col
            }
        }
        // One barrier per chunk: (a) chunk c+1's staged loads complete,
        // (b) all waves done reading buf cur before c+2 re-stages it,
        // (c) coltail ds_writes drained (lgkmcnt).
        __syncthreads();
    }

    // Row fold: m-butterfly entirely on the VALU pipe via DPP. After the 4
    // steps every lane in each 16-lane row holds the fold; lanes m==0 write
    // per-wave partials (rows 16g+4q+r, this wave's 128-j quarter-set).
#pragma unroll
    for (int g = 0; g < 4; ++g)
#pragma unroll
        for (int r = 0; r < 4; ++r) {
            float s = rsum[g][r];
            s += dppf<0xB1>(s);
            s += dppf<0x4E>(s);
            s += dppf<0x141>(s);
            s += dppf<0x140>(s);
            unsigned p = rpk[g][r];
            unsigned o;
            o = dppu<0xB1>(p);  if (o > p) p = o;
            o = dppu<0x4E>(p);  if (o > p) p = o;
            o = dppu<0x141>(p); if (o > p) p = o;
            o = dppu<0x140>(p); if (o > p) p = o;
            if (m == 0) {
                float2 v; v.x = s; v.y = __uint_as_float(p);
                rowtail[w][g * 16 + q * 4 + r] = v;
            }
        }
    __syncthreads();   // tails visible

    // Row epilogue: fold the 4 waves' j-quarter partials, store this
    // j-half's partials (merge folds the 2 halves).
    if (t < 64) {
        float2 v0 = rowtail[0][t], v1 = rowtail[1][t];
        float2 v2 = rowtail[2][t], v3 = rowtail[3][t];
        float s = v0.x + v1.x + v2.x + v3.x;
        unsigned p = __float_as_uint(v0.y);
        unsigned o;
        o = __float_as_uint(v1.y); if (o > p) p = o;
        o = __float_as_uint(v2.y); if (o > p) p = o;
        o = __float_as_uint(v3.y); if (o > p) p = o;
        int idx = (bb << 10) + i0 + t;
        rps[(jh << 15) + idx] = s;
        rpp[(jh << 15) + idx] = p;
    }

    // Col epilogue: coltail is already complete over the block's 64 rows;
    // coalesced store of ONE partial per (block, col).
#pragma unroll
    for (int v = 0; v < 2; ++v) {
        int cj = (v << 8) + t;              // 0..511 within the j-half
        float2 pr = coltail[cj];
        int gidx = (((bb << 4) + it) << 10) + (jh << 9) + cj;
        cps[gidx] = pr.x;
        cpp[gidx] = __float_as_uint(pr.y);
    }
}

// Fold row partials (2 j-halves) and col partials (16 i-tiles) into the
// final stats arrays. Tie-break: umax on packed (bits|inv_index) keeps the
// smaller index on equal truncated value = first-occurrence, matching ref.
__global__ __launch_bounds__(256) void merge_kernel(
        const float* __restrict__ rps, const unsigned* __restrict__ rpp,
        const float* __restrict__ cps, const unsigned* __restrict__ cpp,
        float* __restrict__ row_sum, unsigned* __restrict__ row_pk,
        float* __restrict__ col_sum, unsigned* __restrict__ col_pk) {
    int p = blockIdx.x * 256 + threadIdx.x;   // 32768
    // rows: 2 partials
    float rs = rps[p] + rps[32768 + p];
    unsigned ra = rpp[p], rb = rpp[32768 + p];
    row_sum[p] = rs;
    row_pk[p]  = ra > rb ? ra : rb;
    // cols: 16 partials, stride 1024 dwords (j contiguous -> coalesced)
    int bb = p >> 10, j = p & 1023;
    const float*    cq = cps + (((size_t)bb << 14) + j);
    const unsigned* cr = cpp + (((size_t)bb << 14) + j);
    float s = 0.f;
    unsigned pk = 0u;
#pragma unroll
    for (int k = 0; k < 16; ++k) {
        s += cq[(size_t)k << 10];
        unsigned o = cr[(size_t)k << 10];
        pk = pk > o ? pk : o;
    }
    col_sum[p] = s;
    col_pk[p]  = pk;
}

// Reference broadcasting: trailing /(sum+EPS) factors are indexed by ELEMENT
// position, not by argmax. Writes per-block partials (no atomics, no init).
__global__ __launch_bounds__(256) void loss_kernel2(
        const float* __restrict__ row_sum, const unsigned* __restrict__ row_pk,
        const float* __restrict__ col_sum, const unsigned* __restrict__ col_pk,
        float* __restrict__ partial) {
    int t = blockIdx.x * 256 + threadIdx.x;
    float acc = 0.f;
#pragma unroll
    for (int it = 0; it < 4; ++it) {
        int p = t + it * 16384;
        if (p < NB * LL) {
            unsigned pk2 = row_pk[p];
            float m2 = __uint_as_float(pk2 & 0xFFFFFC00u);
            int j = 1023 - (int)(pk2 & 1023u);
            float s2 = row_sum[p];
            float s1 = col_sum[p];
            unsigned pk1 = col_pk[(p & ~1023) + j];
            float m1 = __uint_as_float(pk1 & 0xFFFFFC00u);
            acc += logf((m2 / (s2 + EPS)) * (m1 / (s1 + EPS)));
        } else {
            int p2 = p - NB * LL;
            unsigned pk1 = col_pk[p2];
            float m1 = __uint_as_float(pk1 & 0xFFFFFC00u);
            int i = 1023 - (int)(pk1 & 1023u);
            float s1 = col_sum[p2];
            float s2 = row_sum[p2];
            unsigned pk2 = row_pk[(p2 & ~1023) + i];
            float m2 = __uint_as_float(pk2 & 0xFFFFFC00u);
            acc += logf((m1 / (s1 + EPS)) * (m2 / (s2 + EPS)));
        }
    }
#pragma unroll
    for (int off = 32; off > 0; off >>= 1) acc += __shfl_down(acc, off, 64);
    __shared__ float wsum[4];
    int lane = threadIdx.x & 63, w = threadIdx.x >> 6;
    if (lane == 0) wsum[w] = acc;
    __syncthreads();
    if (threadIdx.x == 0)
        partial[blockIdx.x] = wsum[0] + wsum[1] + wsum[2] + wsum[3];
}

__global__ void finalize_kernel(const float* __restrict__ partial,
                                float* __restrict__ out) {
    float v = partial[threadIdx.x];
#pragma unroll
    for (int off = 32; off > 0; off >>= 1) v += __shfl_down(v, off, 64);
    if (threadIdx.x == 0) out[0] = -v / (float)(2 * NB * LL);
}

extern "C" void kernel_launch(void* const* d_in, const int* in_sizes, int n_in,
                              void* d_out, int out_size, void* d_ws, size_t ws_size,
                              hipStream_t stream) {
    const float* rgb = (const float*)d_in[0];
    const float* ir  = (const float*)d_in[1];
    char* wsb = (char*)d_ws;

    __bf16*   At      = (__bf16*)(wsb);
    __bf16*   Bt      = (__bf16*)(wsb + 4194304);
    float*    row_sum = (float*)(wsb + 8388608);
    float*    col_sum = (float*)(wsb + 8519680);
    unsigned* row_pk  = (unsigned*)(wsb + 8650752);
    unsigned* col_pk  = (unsigned*)(wsb + 8781824);
    float*    partial = (float*)(wsb + 8912896);
    float*    rps     = (float*)(wsb + 9437184);
    unsigned* rpp     = (unsigned*)(wsb + 9699328);
    float*    cps     = (float*)(wsb + 9961472);
    unsigned* cpp     = (unsigned*)(wsb + 12058624);

    transpose_norm_kernel<<<1024, 256, 0, stream>>>(rgb, ir, At, Bt);
    gemm_stats_kernel<<<1024, 256, 0, stream>>>(At, Bt, rps, rpp, cps, cpp);
    merge_kernel<<<128, 256, 0, stream>>>(rps, rpp, cps, cpp,
                                          row_sum, row_pk, col_sum, col_pk);
    loss_kernel2<<<64, 256, 0, stream>>>(row_sum, row_pk, col_sum, col_pk, partial);
    finalize_kernel<<<1, 64, 0, stream>>>(partial, (float*)d_out);
}